// Round 1
// baseline (253.438 us; speedup 1.0000x reference)
//
#include <hip/hip_runtime.h>
#include <hip/hip_bf16.h>

// Fused per-type MLP chain (Linear -> ResBlock(silu,LN,Linear) -> silu-Linear -> dot)
// R6 (from R5 @ 223.6us / fused 120us):
//  1) VALU diet: v_cvt_pk_bf16_f32 for all f32->bf16 packing (was ~4-op RNE
//     bit-twiddle per value, duplicated in epi1); silu via v_rcp_f32 (was
//     full-precision div sequence). Predicted VALUBusy 26% -> ~15%.
//  2) LDS diet 45568 -> 38912 B => 4 blocks/CU (was 3; grid 1028 ~= 1024 = one
//     clean round). Per-layer bias/alpha vectors restaged into 2 shared arrays
//     in the sync-shadow of each GEMM; muS/rsS folded into red1/red2.
//  3) Prep merge: single k_prep (wave-aggregated atomics, capacity-region perm
//     at t*N) replaces k_hist+k_scatter. ws usage ~3.1 MB.
// MFMA 16x16x32 bf16 layouts (HW-verified per guide m89/m91):
//   A[m][k]: m = lane&15, k = (lane>>4)*8 + j   (W row-major: contiguous 16B)
//   B[k][n]: n = lane&15, k = (lane>>4)*8 + j   (Xs row  : contiguous 16B)
//   C/D:     n(atom) = lane&15, m(neuron) = (lane>>4)*4 + reg

#define D 256
#define T 4
#define MT 64            // atoms per block
#define NTHREADS 256     // 4 waves
#define LDSTRIDE 264     // padded LDS row stride (bf16): 528B rows stay 16B-aligned

typedef __attribute__((ext_vector_type(8))) short bf16x8;
typedef __attribute__((ext_vector_type(4))) float f32x4;

__device__ __forceinline__ float bf2f(unsigned short s) {
    union { unsigned u; float f; } c;
    c.u = ((unsigned)s) << 16;
    return c.f;
}
// packed f32x2 -> bf16x2, RNE (MODE default), 1 instr (guide T12 recipe, m240)
__device__ __forceinline__ unsigned cvtpk(float a, float b) {
    unsigned r;
    asm("v_cvt_pk_bf16_f32 %0, %1, %2" : "=v"(r) : "v"(a), "v"(b));
    return r;
}
__device__ __forceinline__ float lo2f(unsigned u) { return bf2f((unsigned short)(u & 0xffffu)); }
__device__ __forceinline__ float hi2f(unsigned u) { return bf2f((unsigned short)(u >> 16)); }
__device__ __forceinline__ float silu(float v) {
    // fast rcp (~1ulp) is fine: result is rounded to bf16 anyway
    return v * __builtin_amdgcn_rcpf(1.f + __expf(-v));
}

// ---------------- prep kernel (hist+scatter+convert merged) ----------------
// perm layout: capacity regions, type t's atoms at perm[t*N .. t*N+count[t])
// (intra-type order irrelevant to the math; output scattered via perm).
extern "C" __global__ void k_prep(const int* __restrict__ species, int* cursors,
                                  int* __restrict__ perm, int N,
                                  const float* __restrict__ s0, const float* __restrict__ s1,
                                  const float* __restrict__ s2, const float* __restrict__ s3,
                                  unsigned short* __restrict__ d0, unsigned short* __restrict__ d1,
                                  unsigned short* __restrict__ d2, unsigned short* __restrict__ d3, int n4) {
    int i = blockIdx.x * blockDim.x + threadIdx.x;
    if (i < n4) {   // weight fp32 -> bf16 (vectorized, cvt_pk)
        float4 v;
        v = ((const float4*)s0)[i]; ((uint2*)d0)[i] = make_uint2(cvtpk(v.x, v.y), cvtpk(v.z, v.w));
        v = ((const float4*)s1)[i]; ((uint2*)d1)[i] = make_uint2(cvtpk(v.x, v.y), cvtpk(v.z, v.w));
        v = ((const float4*)s2)[i]; ((uint2*)d2)[i] = make_uint2(cvtpk(v.x, v.y), cvtpk(v.z, v.w));
        v = ((const float4*)s3)[i]; ((uint2*)d3)[i] = make_uint2(cvtpk(v.x, v.y), cvtpk(v.z, v.w));
    }
    if (i < N) {
        int t = species[i];
        int lane = threadIdx.x & 63;
        int idx = 0;
#pragma unroll
        for (int tt = 0; tt < T; ++tt) {
            unsigned long long m = __ballot(t == tt);   // 4 atomics/wave, not 64
            if (t == tt) {
                int rank = __popcll(m & ((1ull << lane) - 1ull));
                int leader = __builtin_ctzll(m);
                int b = 0;
                if (lane == leader) b = atomicAdd(&cursors[tt], __popcll(m));
                b = __shfl(b, leader, 64);
                idx = b + rank;
            }
        }
        perm[t * N + idx] = i;
    }
}

// ---------------- fused main kernel ----------------

extern "C" __global__ void __launch_bounds__(NTHREADS, 2)
fused_moe(const float* __restrict__ density,
          const int* __restrict__ perm,
          const int* __restrict__ counts,     // == cursors after k_prep
          const unsigned short* __restrict__ W0b,
          const unsigned short* __restrict__ Wab,
          const unsigned short* __restrict__ Wlb,
          const unsigned short* __restrict__ Wfb,
          const float* __restrict__ b0g, const float* __restrict__ bag,
          const float* __restrict__ aag, const float* __restrict__ gg,
          const float* __restrict__ btg, const float* __restrict__ blg,
          const float* __restrict__ bfg, const float* __restrict__ afg,
          const float* __restrict__ Wog, const float* __restrict__ bog,
          float* __restrict__ out, int N)
{
    __shared__ unsigned short Xs[MT * LDSTRIDE];        // 33792 B
    __shared__ float Pbias[D], Palpha[D];               // restaged per phase (2048 B)
    __shared__ float Pwo[D];                            // persistent (1024 B)
    __shared__ float red1[NTHREADS], red2[NTHREADS];    // 2048 B; also carries mu/rs
    // total LDS = 38912 B -> 4 blocks/CU

    const int tid = threadIdx.x;

    // ---- which (type, tile) am I? ----
    int c[T];
#pragma unroll
    for (int i = 0; i < T; ++i) c[i] = counts[i];
    int t = -1, tile = 0, rem = blockIdx.x;
#pragma unroll
    for (int i = 0; i < T; ++i) {
        int ti = (c[i] + MT - 1) >> 6;
        if (t < 0) {
            if (rem < ti) { t = i; tile = rem; }
            else rem -= ti;
        }
    }
    if (t < 0) return;
    const int bstart = t * N + tile * MT;               // capacity-region base
    const int nrows = min(MT, c[t] - tile * MT);

    // ---- stage layer-1 bias + output weights ----
    Pbias[tid] = b0g[t * D + tid];
    Pwo[tid]   = Wog[t * D + tid];

    // ---- gather X0 (fp32 -> bf16) into LDS: Xs[atom][feature] ----
#pragma unroll
    for (int p = 0; p < 4; ++p) {
        int row = p * 16 + (tid >> 4);
        int cbase = (tid & 15) * 4;
        unsigned short* dst = Xs + row * LDSTRIDE;
        if (row < nrows) {
            const float* src = density + (size_t)perm[bstart + row] * D;
#pragma unroll
            for (int j = 0; j < 4; ++j) {
                int col = cbase + j * 64;
                float4 v = *(const float4*)(src + col);
                *(uint2*)(dst + col) = make_uint2(cvtpk(v.x, v.y), cvtpk(v.z, v.w));
            }
        } else {
#pragma unroll
            for (int j = 0; j < 4; ++j)
                *(uint2*)(dst + cbase + j * 64) = make_uint2(0u, 0u);
        }
    }
    __syncthreads();

    const int lane = tid & 63;
    const int w    = tid >> 6;            // wave id -> neuron quarter
    const int ml   = lane & 15;
    const int qk   = (lane >> 4) * 8;     // A/B fragment k offset
    const int qr   = (lane >> 4) * 4;     // C/D fragment neuron offset

    const size_t wmat = (size_t)t * D * D;
    const unsigned short* W0t = W0b + wmat;
    const unsigned short* Wat = Wab + wmat;
    const unsigned short* Wlt = Wlb + wmat;
    const unsigned short* Wft = Wfb + wmat;

    f32x4 acc[4][4];
    const f32x4 zero4 = {0.f, 0.f, 0.f, 0.f};

    // D[m=neuron][n=atom]: A = W rows (global/L2), B = Xs rows (LDS)
    auto do_gemm = [&](const unsigned short* __restrict__ W) {
#pragma unroll
        for (int mi = 0; mi < 4; ++mi)
#pragma unroll
            for (int ni = 0; ni < 4; ++ni) acc[mi][ni] = zero4;
#pragma unroll
        for (int k0 = 0; k0 < D; k0 += 32) {
            bf16x8 a[4], b[4];
#pragma unroll
            for (int mi = 0; mi < 4; ++mi)
                a[mi] = *(const bf16x8*)(W + (size_t)(w * 64 + mi * 16 + ml) * D + k0 + qk);
#pragma unroll
            for (int ni = 0; ni < 4; ++ni)
                b[ni] = *(const bf16x8*)(Xs + (ni * 16 + ml) * LDSTRIDE + k0 + qk);
#pragma unroll
            for (int mi = 0; mi < 4; ++mi)
#pragma unroll
                for (int ni = 0; ni < 4; ++ni)
                    acc[mi][ni] = __builtin_amdgcn_mfma_f32_16x16x32_bf16(a[mi], b[ni], acc[mi][ni], 0, 0, 0);
        }
    };

    // lane owns atom a0 = ni*16+ml, neurons r0..r0+3 (contiguous)

    // ======== Layer 1: x1 = X0 @ W0^T + b0 ========
    do_gemm(W0t);
    __syncthreads();
    unsigned res[4][4][2];   // x1 saved PACKED BF16 (32 VGPRs)
#pragma unroll
    for (int mi = 0; mi < 4; ++mi) {
#pragma unroll
        for (int ni = 0; ni < 4; ++ni) {
            int r0 = w * 64 + mi * 16 + qr;
            int a0 = ni * 16 + ml;
            float4 bb = *(const float4*)(Pbias + r0);
            unsigned p01 = cvtpk(acc[mi][ni][0] + bb.x, acc[mi][ni][1] + bb.y);
            unsigned p23 = cvtpk(acc[mi][ni][2] + bb.z, acc[mi][ni][3] + bb.w);
            res[mi][ni][0] = p01;
            res[mi][ni][1] = p23;
            *(uint2*)(Xs + a0 * LDSTRIDE + r0) = make_uint2(p01, p23);
        }
    }
    __syncthreads();

    // ======== Layer 2: h = alpha_a * silu(x1 @ Wa^T + ba) ========
    Pbias[tid]  = bag[t * D + tid];     // restage in gemm's sync-shadow
    Palpha[tid] = aag[t * D + tid];
    do_gemm(Wat);
    __syncthreads();
#pragma unroll
    for (int mi = 0; mi < 4; ++mi) {
#pragma unroll
        for (int ni = 0; ni < 4; ++ni) {
            int r0 = w * 64 + mi * 16 + qr;
            int a0 = ni * 16 + ml;
            float4 bb = *(const float4*)(Pbias + r0);
            float4 aa = *(const float4*)(Palpha + r0);
            float v0 = aa.x * silu(acc[mi][ni][0] + bb.x);
            float v1 = aa.y * silu(acc[mi][ni][1] + bb.y);
            float v2 = aa.z * silu(acc[mi][ni][2] + bb.z);
            float v3 = aa.w * silu(acc[mi][ni][3] + bb.w);
            *(uint2*)(Xs + a0 * LDSTRIDE + r0) = make_uint2(cvtpk(v0, v1), cvtpk(v2, v3));
        }
    }
    __syncthreads();

    // ======== LayerNorm per atom over 256 neurons (in LDS) ========
    {
        Pbias[tid]  = gg[t * D + tid];      // gamma (read after stats sync)
        Palpha[tid] = btg[t * D + tid];     // beta
        int row = tid & 63, q = tid >> 6;   // octet spans 32 banks: conflict-free
        const bf16x8* base = (const bf16x8*)(Xs + row * LDSTRIDE + q * 64);
        bf16x8 hv[8];
        float sum = 0.f, ssq = 0.f;
#pragma unroll
        for (int j = 0; j < 8; ++j) {
            hv[j] = base[j];
#pragma unroll
            for (int e = 0; e < 8; ++e) {
                float f = bf2f((unsigned short)hv[j][e]);
                sum += f;
                ssq = fmaf(f, f, ssq);
            }
        }
        red1[tid] = sum; red2[tid] = ssq;
        __syncthreads();
        if (tid < MT) {
            float s  = red1[tid] + red1[tid + 64] + red1[tid + 128] + red1[tid + 192];
            float sq = red2[tid] + red2[tid + 64] + red2[tid + 128] + red2[tid + 192];
            float mu = s * (1.f / D);
            float var = sq * (1.f / D) - mu * mu;
            red1[tid] = mu;                       // fold muS/rsS into red arrays
            red2[tid] = rsqrtf(var + 1e-5f);
        }
        __syncthreads();
        float mu = red1[row], rs = red2[row];
        unsigned short* wb = Xs + row * LDSTRIDE + q * 64;
#pragma unroll
        for (int j = 0; j < 8; ++j) {
            float n[8];
#pragma unroll
            for (int e = 0; e < 8; ++e) {
                int col = q * 64 + j * 8 + e;
                float f = bf2f((unsigned short)hv[j][e]);
                n[e] = fmaf((f - mu) * rs, Pbias[col], Palpha[col]);
            }
            uint4 o = make_uint4(cvtpk(n[0], n[1]), cvtpk(n[2], n[3]),
                                 cvtpk(n[4], n[5]), cvtpk(n[6], n[7]));
            *(uint4*)(wb + j * 8) = o;
        }
    }
    __syncthreads();

    // ======== Layer 3: x3 = x1 + h @ Wl^T + bl ========
    Pbias[tid] = blg[t * D + tid];
    do_gemm(Wlt);
    __syncthreads();
#pragma unroll
    for (int mi = 0; mi < 4; ++mi) {
#pragma unroll
        for (int ni = 0; ni < 4; ++ni) {
            int r0 = w * 64 + mi * 16 + qr;
            int a0 = ni * 16 + ml;
            float4 bb = *(const float4*)(Pbias + r0);
            float v0 = acc[mi][ni][0] + bb.x + lo2f(res[mi][ni][0]);
            float v1 = acc[mi][ni][1] + bb.y + hi2f(res[mi][ni][0]);
            float v2 = acc[mi][ni][2] + bb.z + lo2f(res[mi][ni][1]);
            float v3 = acc[mi][ni][3] + bb.w + hi2f(res[mi][ni][1]);
            *(uint2*)(Xs + a0 * LDSTRIDE + r0) = make_uint2(cvtpk(v0, v1), cvtpk(v2, v3));
        }
    }
    __syncthreads();

    // ======== Layer 4: x4 = alpha_f * silu(x3 @ Wf^T + bf) ========
    Pbias[tid]  = bfg[t * D + tid];
    Palpha[tid] = afg[t * D + tid];
    do_gemm(Wft);
    __syncthreads();
#pragma unroll
    for (int mi = 0; mi < 4; ++mi) {
#pragma unroll
        for (int ni = 0; ni < 4; ++ni) {
            int r0 = w * 64 + mi * 16 + qr;
            int a0 = ni * 16 + ml;
            float4 bb = *(const float4*)(Pbias + r0);
            float4 aa = *(const float4*)(Palpha + r0);
            float v0 = aa.x * silu(acc[mi][ni][0] + bb.x);
            float v1 = aa.y * silu(acc[mi][ni][1] + bb.y);
            float v2 = aa.z * silu(acc[mi][ni][2] + bb.z);
            float v3 = aa.w * silu(acc[mi][ni][3] + bb.w);
            *(uint2*)(Xs + a0 * LDSTRIDE + r0) = make_uint2(cvtpk(v0, v1), cvtpk(v2, v3));
        }
    }
    __syncthreads();

    // ======== Output: y = x4 . Wo[t] + bo[t] ========
    {
        int row = tid & 63, q = tid >> 6;
        const bf16x8* base = (const bf16x8*)(Xs + row * LDSTRIDE + q * 64);
        float part = 0.f;
#pragma unroll
        for (int j = 0; j < 8; ++j) {
            bf16x8 hv = base[j];
#pragma unroll
            for (int e = 0; e < 8; ++e)
                part = fmaf(bf2f((unsigned short)hv[e]), Pwo[q * 64 + j * 8 + e], part);
        }
        red1[tid] = part;
        __syncthreads();
        if (tid < nrows) {
            float val = red1[tid] + red1[tid + 64] + red1[tid + 128] + red1[tid + 192] + bog[t];
            out[perm[bstart + tid]] = val;
        }
    }
}

// ---------------- launcher ----------------

extern "C" void kernel_launch(void* const* d_in, const int* in_sizes, int n_in,
                              void* d_out, int out_size, void* d_ws, size_t ws_size,
                              hipStream_t stream) {
    const float* density = (const float*)d_in[0];
    const int*   species = (const int*)d_in[1];
    const float* W0      = (const float*)d_in[2];
    const float* b0      = (const float*)d_in[3];
    const float* Wa      = (const float*)d_in[4];
    const float* ba      = (const float*)d_in[5];
    const float* alpha_a = (const float*)d_in[6];
    const float* gamma   = (const float*)d_in[7];
    const float* beta_ln = (const float*)d_in[8];
    const float* Wl      = (const float*)d_in[9];
    const float* bl      = (const float*)d_in[10];
    const float* Wf      = (const float*)d_in[11];
    const float* bfv     = (const float*)d_in[12];
    const float* alpha_f = (const float*)d_in[13];
    const float* Wo      = (const float*)d_in[14];
    const float* bo      = (const float*)d_in[15];
    float* out = (float*)d_out;
    const int N = in_sizes[1];

    // ws layout: [cursors 16B pad to 64] [perm T*N ints = 1MB] [bf16 weights 4 x 512KB]
    char* ws = (char*)d_ws;
    int* cursors = (int*)ws;
    int* perm    = (int*)(ws + 64);
    const size_t wsz = (size_t)T * D * D;       // elems per weight tensor
    unsigned short* W0b = (unsigned short*)(ws + 64 + (size_t)T * N * 4);
    unsigned short* Wab = W0b + wsz;
    unsigned short* Wlb = Wab + wsz;
    unsigned short* Wfb = Wlb + wsz;

    hipMemsetAsync(ws, 0, 16, stream);          // cursors
    int n4 = (int)(wsz / 4);
    int pb = ((N > n4 ? N : n4) + 255) / 256;
    k_prep<<<pb, 256, 0, stream>>>(species, cursors, perm, N, W0, Wa, Wl, Wf,
                                   W0b, Wab, Wlb, Wfb, n4);

    int nblocks = (N + MT - 1) / MT + T;
    fused_moe<<<nblocks, NTHREADS, 0, stream>>>(density, perm, cursors, W0b, Wab, Wlb, Wfb,
                                                b0, ba, alpha_a, gamma, beta_ln, bl, bfv, alpha_f,
                                                Wo, bo, out, N);
}

// Round 2
// 201.227 us; speedup vs baseline: 1.2595x; 1.2595x over previous
//
#include <hip/hip_runtime.h>
#include <hip/hip_bf16.h>

// Fused per-type MLP chain (Linear -> ResBlock(silu,LN,Linear) -> silu-Linear -> dot)
// R7 (from R6 @ 253us total / fused 110us):
//  1) OCCUPANCY FIX: R6's VGPR_Count=92 was arch-only; +64 AGPR (acc[4][4]) =
//     156 total > 128 -> only 2 waves/SIMD. Restructure to 8 waves x (32
//     neurons x 64 atoms): acc[2][4]=32 AGPR, res=16 VGPR, __launch_bounds__
//     (512,4) forces <=128 total -> 4 waves/SIMD = 16 waves/CU (2x residency).
//  2) PREP ATOMIC FIX: R6's 4096 wave-level atomics all hit ONE cache line
//     (cursors[0..3] in 16B) -> cross-XCD line ping-pong ~20ns each (+40us
//     vs R5). Restore block-level LDS histogram (1024 atomics) AND pad each
//     cursor to its own 128B line.
// MFMA 16x16x32 bf16 layouts (HW-verified per guide m89/m91):
//   A[m][k]: m = lane&15, k = (lane>>4)*8 + j   (W row-major: contiguous 16B)
//   B[k][n]: n = lane&15, k = (lane>>4)*8 + j   (Xs row  : contiguous 16B)
//   C/D:     n(atom) = lane&15, m(neuron) = (lane>>4)*4 + reg

#define D 256
#define T 4
#define MT 64            // atoms per block
#define NTHREADS 512     // 8 waves
#define LDSTRIDE 264     // padded LDS row stride (bf16): 528B rows stay 16B-aligned
#define CSTRIDE 32       // cursor padding: one counter per 128B cache line

typedef __attribute__((ext_vector_type(8))) short bf16x8;
typedef __attribute__((ext_vector_type(4))) float f32x4;

__device__ __forceinline__ float bf2f(unsigned short s) {
    union { unsigned u; float f; } c;
    c.u = ((unsigned)s) << 16;
    return c.f;
}
// packed f32x2 -> bf16x2, RNE (MODE default), 1 instr (guide T12 recipe, m240)
__device__ __forceinline__ unsigned cvtpk(float a, float b) {
    unsigned r;
    asm("v_cvt_pk_bf16_f32 %0, %1, %2" : "=v"(r) : "v"(a), "v"(b));
    return r;
}
__device__ __forceinline__ float lo2f(unsigned u) { return bf2f((unsigned short)(u & 0xffffu)); }
__device__ __forceinline__ float hi2f(unsigned u) { return bf2f((unsigned short)(u >> 16)); }
__device__ __forceinline__ float silu(float v) {
    // fast rcp (~1ulp) is fine: result is rounded to bf16 anyway
    return v * __builtin_amdgcn_rcpf(1.f + __expf(-v));
}

// ---------------- prep kernel (hist+scatter+convert merged) ----------------
// perm layout: capacity regions, type t's atoms at perm[t*N .. t*N+count[t])
// (intra-type order irrelevant to the math; output scattered via perm).
extern "C" __global__ void k_prep(const int* __restrict__ species, int* cursors,
                                  int* __restrict__ perm, int N,
                                  const float* __restrict__ s0, const float* __restrict__ s1,
                                  const float* __restrict__ s2, const float* __restrict__ s3,
                                  unsigned short* __restrict__ d0, unsigned short* __restrict__ d1,
                                  unsigned short* __restrict__ d2, unsigned short* __restrict__ d3, int n4) {
    __shared__ int lh[T], lbase[T];
    int tid = threadIdx.x;
    if (tid < T) lh[tid] = 0;
    __syncthreads();
    int i = blockIdx.x * blockDim.x + tid;
    int t = -1, rank = 0;
    if (i < N) {
        t = species[i];
        rank = atomicAdd(&lh[t], 1);          // LDS atomic: block-local rank
    }
    if (i < n4) {   // weight fp32 -> bf16 (vectorized, cvt_pk); independent path
        float4 v;
        v = ((const float4*)s0)[i]; ((uint2*)d0)[i] = make_uint2(cvtpk(v.x, v.y), cvtpk(v.z, v.w));
        v = ((const float4*)s1)[i]; ((uint2*)d1)[i] = make_uint2(cvtpk(v.x, v.y), cvtpk(v.z, v.w));
        v = ((const float4*)s2)[i]; ((uint2*)d2)[i] = make_uint2(cvtpk(v.x, v.y), cvtpk(v.z, v.w));
        v = ((const float4*)s3)[i]; ((uint2*)d3)[i] = make_uint2(cvtpk(v.x, v.y), cvtpk(v.z, v.w));
    }
    __syncthreads();
    if (tid < T) lbase[tid] = atomicAdd(&cursors[tid * CSTRIDE], lh[tid]);  // 4/block, padded lines
    __syncthreads();
    if (t >= 0) perm[t * N + lbase[t] + rank] = i;
}

// ---------------- fused main kernel ----------------

extern "C" __global__ void __launch_bounds__(NTHREADS, 4)
fused_moe(const float* __restrict__ density,
          const int* __restrict__ perm,
          const int* __restrict__ counts,     // == padded cursors after k_prep
          const unsigned short* __restrict__ W0b,
          const unsigned short* __restrict__ Wab,
          const unsigned short* __restrict__ Wlb,
          const unsigned short* __restrict__ Wfb,
          const float* __restrict__ b0g, const float* __restrict__ bag,
          const float* __restrict__ aag, const float* __restrict__ gg,
          const float* __restrict__ btg, const float* __restrict__ blg,
          const float* __restrict__ bfg, const float* __restrict__ afg,
          const float* __restrict__ Wog, const float* __restrict__ bog,
          float* __restrict__ out, int N)
{
    __shared__ unsigned short Xs[MT * LDSTRIDE];        // 33792 B
    __shared__ float Pbias[D], Palpha[D];               // restaged per phase (2048 B)
    __shared__ float Pwo[D];                            // persistent (1024 B)
    __shared__ float red1[NTHREADS], red2[NTHREADS];    // 4096 B; also carries mu/rs
    // total LDS = 40960 B (not binding; VGPR<=128 -> 16 waves/CU = 2 blocks)

    const int tid = threadIdx.x;

    // ---- which (type, tile) am I? ----
    int c[T];
#pragma unroll
    for (int i = 0; i < T; ++i) c[i] = counts[i * CSTRIDE];
    int t = -1, tile = 0, rem = blockIdx.x;
#pragma unroll
    for (int i = 0; i < T; ++i) {
        int ti = (c[i] + MT - 1) >> 6;
        if (t < 0) {
            if (rem < ti) { t = i; tile = rem; }
            else rem -= ti;
        }
    }
    if (t < 0) return;
    const int bstart = t * N + tile * MT;               // capacity-region base
    const int nrows = min(MT, c[t] - tile * MT);

    // ---- stage layer-1 bias + output weights ----
    if (tid < D) {
        Pbias[tid] = b0g[t * D + tid];
        Pwo[tid]   = Wog[t * D + tid];
    }

    // ---- gather X0 (fp32 -> bf16) into LDS: Xs[atom][feature] ----
#pragma unroll
    for (int p = 0; p < 2; ++p) {
        int row = p * 32 + (tid >> 4);
        int cbase = (tid & 15) * 4;
        unsigned short* dst = Xs + row * LDSTRIDE;
        if (row < nrows) {
            const float* src = density + (size_t)perm[bstart + row] * D;
#pragma unroll
            for (int j = 0; j < 4; ++j) {
                int col = cbase + j * 64;
                float4 v = *(const float4*)(src + col);
                *(uint2*)(dst + col) = make_uint2(cvtpk(v.x, v.y), cvtpk(v.z, v.w));
            }
        } else {
#pragma unroll
            for (int j = 0; j < 4; ++j)
                *(uint2*)(dst + cbase + j * 64) = make_uint2(0u, 0u);
        }
    }
    __syncthreads();

    const int lane = tid & 63;
    const int w    = tid >> 6;            // wave id 0..7 -> neuron 32-slice
    const int ml   = lane & 15;
    const int qk   = (lane >> 4) * 8;     // A/B fragment k offset
    const int qr   = (lane >> 4) * 4;     // C/D fragment neuron offset

    const size_t wmat = (size_t)t * D * D;
    const unsigned short* W0t = W0b + wmat;
    const unsigned short* Wat = Wab + wmat;
    const unsigned short* Wlt = Wlb + wmat;
    const unsigned short* Wft = Wfb + wmat;

    f32x4 acc[2][4];                      // 32 AGPRs (was 64)
    const f32x4 zero4 = {0.f, 0.f, 0.f, 0.f};

    // D[m=neuron][n=atom]: A = W rows (global/L2), B = Xs rows (LDS)
    auto do_gemm = [&](const unsigned short* __restrict__ W) {
#pragma unroll
        for (int mi = 0; mi < 2; ++mi)
#pragma unroll
            for (int ni = 0; ni < 4; ++ni) acc[mi][ni] = zero4;
#pragma unroll
        for (int k0 = 0; k0 < D; k0 += 32) {
            bf16x8 a[2], b[4];
#pragma unroll
            for (int mi = 0; mi < 2; ++mi)
                a[mi] = *(const bf16x8*)(W + (size_t)(w * 32 + mi * 16 + ml) * D + k0 + qk);
#pragma unroll
            for (int ni = 0; ni < 4; ++ni)
                b[ni] = *(const bf16x8*)(Xs + (ni * 16 + ml) * LDSTRIDE + k0 + qk);
#pragma unroll
            for (int mi = 0; mi < 2; ++mi)
#pragma unroll
                for (int ni = 0; ni < 4; ++ni)
                    acc[mi][ni] = __builtin_amdgcn_mfma_f32_16x16x32_bf16(a[mi], b[ni], acc[mi][ni], 0, 0, 0);
        }
    };

    // lane owns atom a0 = ni*16+ml, neurons r0..r0+3 (contiguous)

    // ======== Layer 1: x1 = X0 @ W0^T + b0 ========
    do_gemm(W0t);
    __syncthreads();
    unsigned res[2][4][2];   // x1 saved PACKED BF16 (16 VGPRs)
#pragma unroll
    for (int mi = 0; mi < 2; ++mi) {
#pragma unroll
        for (int ni = 0; ni < 4; ++ni) {
            int r0 = w * 32 + mi * 16 + qr;
            int a0 = ni * 16 + ml;
            float4 bb = *(const float4*)(Pbias + r0);
            unsigned p01 = cvtpk(acc[mi][ni][0] + bb.x, acc[mi][ni][1] + bb.y);
            unsigned p23 = cvtpk(acc[mi][ni][2] + bb.z, acc[mi][ni][3] + bb.w);
            res[mi][ni][0] = p01;
            res[mi][ni][1] = p23;
            *(uint2*)(Xs + a0 * LDSTRIDE + r0) = make_uint2(p01, p23);
        }
    }
    __syncthreads();

    // ======== Layer 2: h = alpha_a * silu(x1 @ Wa^T + ba) ========
    if (tid < D) {
        Pbias[tid]  = bag[t * D + tid];     // restage in gemm's sync-shadow
        Palpha[tid] = aag[t * D + tid];
    }
    do_gemm(Wat);
    __syncthreads();
#pragma unroll
    for (int mi = 0; mi < 2; ++mi) {
#pragma unroll
        for (int ni = 0; ni < 4; ++ni) {
            int r0 = w * 32 + mi * 16 + qr;
            int a0 = ni * 16 + ml;
            float4 bb = *(const float4*)(Pbias + r0);
            float4 aa = *(const float4*)(Palpha + r0);
            float v0 = aa.x * silu(acc[mi][ni][0] + bb.x);
            float v1 = aa.y * silu(acc[mi][ni][1] + bb.y);
            float v2 = aa.z * silu(acc[mi][ni][2] + bb.z);
            float v3 = aa.w * silu(acc[mi][ni][3] + bb.w);
            *(uint2*)(Xs + a0 * LDSTRIDE + r0) = make_uint2(cvtpk(v0, v1), cvtpk(v2, v3));
        }
    }
    __syncthreads();

    // ======== LayerNorm per atom over 256 neurons (in LDS) ========
    {
        if (tid < D) {
            Pbias[tid]  = gg[t * D + tid];      // gamma (read after stats sync)
            Palpha[tid] = btg[t * D + tid];     // beta
        }
        int row = tid & 63, q = tid >> 6;   // thread covers 32 columns
        const bf16x8* base = (const bf16x8*)(Xs + row * LDSTRIDE + q * 32);
        bf16x8 hv[4];
        float sum = 0.f, ssq = 0.f;
#pragma unroll
        for (int j = 0; j < 4; ++j) {
            hv[j] = base[j];
#pragma unroll
            for (int e = 0; e < 8; ++e) {
                float f = bf2f((unsigned short)hv[j][e]);
                sum += f;
                ssq = fmaf(f, f, ssq);
            }
        }
        red1[tid] = sum; red2[tid] = ssq;
        __syncthreads();
        if (tid < MT) {
            float s = 0.f, sq = 0.f;
#pragma unroll
            for (int k = 0; k < 8; ++k) { s += red1[tid + 64 * k]; sq += red2[tid + 64 * k]; }
            float mu = s * (1.f / D);
            float var = sq * (1.f / D) - mu * mu;
            red1[tid] = mu;                       // fold muS/rsS into red arrays
            red2[tid] = rsqrtf(var + 1e-5f);
        }
        __syncthreads();
        float mu = red1[row], rs = red2[row];
        unsigned short* wb = Xs + row * LDSTRIDE + q * 32;
#pragma unroll
        for (int j = 0; j < 4; ++j) {
            float n[8];
#pragma unroll
            for (int e = 0; e < 8; ++e) {
                int col = q * 32 + j * 8 + e;
                float f = bf2f((unsigned short)hv[j][e]);
                n[e] = fmaf((f - mu) * rs, Pbias[col], Palpha[col]);
            }
            uint4 o = make_uint4(cvtpk(n[0], n[1]), cvtpk(n[2], n[3]),
                                 cvtpk(n[4], n[5]), cvtpk(n[6], n[7]));
            *(uint4*)(wb + j * 8) = o;
        }
    }
    __syncthreads();

    // ======== Layer 3: x3 = x1 + h @ Wl^T + bl ========
    if (tid < D) Pbias[tid] = blg[t * D + tid];
    do_gemm(Wlt);
    __syncthreads();
#pragma unroll
    for (int mi = 0; mi < 2; ++mi) {
#pragma unroll
        for (int ni = 0; ni < 4; ++ni) {
            int r0 = w * 32 + mi * 16 + qr;
            int a0 = ni * 16 + ml;
            float4 bb = *(const float4*)(Pbias + r0);
            float v0 = acc[mi][ni][0] + bb.x + lo2f(res[mi][ni][0]);
            float v1 = acc[mi][ni][1] + bb.y + hi2f(res[mi][ni][0]);
            float v2 = acc[mi][ni][2] + bb.z + lo2f(res[mi][ni][1]);
            float v3 = acc[mi][ni][3] + bb.w + hi2f(res[mi][ni][1]);
            *(uint2*)(Xs + a0 * LDSTRIDE + r0) = make_uint2(cvtpk(v0, v1), cvtpk(v2, v3));
        }
    }
    __syncthreads();

    // ======== Layer 4: x4 = alpha_f * silu(x3 @ Wf^T + bf) ========
    if (tid < D) {
        Pbias[tid]  = bfg[t * D + tid];
        Palpha[tid] = afg[t * D + tid];
    }
    do_gemm(Wft);
    __syncthreads();
#pragma unroll
    for (int mi = 0; mi < 2; ++mi) {
#pragma unroll
        for (int ni = 0; ni < 4; ++ni) {
            int r0 = w * 32 + mi * 16 + qr;
            int a0 = ni * 16 + ml;
            float4 bb = *(const float4*)(Pbias + r0);
            float4 aa = *(const float4*)(Palpha + r0);
            float v0 = aa.x * silu(acc[mi][ni][0] + bb.x);
            float v1 = aa.y * silu(acc[mi][ni][1] + bb.y);
            float v2 = aa.z * silu(acc[mi][ni][2] + bb.z);
            float v3 = aa.w * silu(acc[mi][ni][3] + bb.w);
            *(uint2*)(Xs + a0 * LDSTRIDE + r0) = make_uint2(cvtpk(v0, v1), cvtpk(v2, v3));
        }
    }
    __syncthreads();

    // ======== Output: y = x4 . Wo[t] + bo[t] ========
    {
        int row = tid & 63, q = tid >> 6;
        const bf16x8* base = (const bf16x8*)(Xs + row * LDSTRIDE + q * 32);
        float part = 0.f;
#pragma unroll
        for (int j = 0; j < 4; ++j) {
            bf16x8 hv = base[j];
#pragma unroll
            for (int e = 0; e < 8; ++e)
                part = fmaf(bf2f((unsigned short)hv[e]), Pwo[q * 32 + j * 8 + e], part);
        }
        red1[tid] = part;
        __syncthreads();
        if (tid < nrows) {
            float val = bog[t];
#pragma unroll
            for (int k = 0; k < 8; ++k) val += red1[tid + 64 * k];
            out[perm[bstart + tid]] = val;
        }
    }
}

// ---------------- launcher ----------------

extern "C" void kernel_launch(void* const* d_in, const int* in_sizes, int n_in,
                              void* d_out, int out_size, void* d_ws, size_t ws_size,
                              hipStream_t stream) {
    const float* density = (const float*)d_in[0];
    const int*   species = (const int*)d_in[1];
    const float* W0      = (const float*)d_in[2];
    const float* b0      = (const float*)d_in[3];
    const float* Wa      = (const float*)d_in[4];
    const float* ba      = (const float*)d_in[5];
    const float* alpha_a = (const float*)d_in[6];
    const float* gamma   = (const float*)d_in[7];
    const float* beta_ln = (const float*)d_in[8];
    const float* Wl      = (const float*)d_in[9];
    const float* bl      = (const float*)d_in[10];
    const float* Wf      = (const float*)d_in[11];
    const float* bfv     = (const float*)d_in[12];
    const float* alpha_f = (const float*)d_in[13];
    const float* Wo      = (const float*)d_in[14];
    const float* bo      = (const float*)d_in[15];
    float* out = (float*)d_out;
    const int N = in_sizes[1];

    // ws layout: [cursors 4 x 128B = 512B, pad to 1KB] [perm T*N ints = 1MB]
    //            [bf16 weights 4 x 512KB]
    char* ws = (char*)d_ws;
    int* cursors = (int*)ws;
    int* perm    = (int*)(ws + 1024);
    const size_t wsz = (size_t)T * D * D;       // elems per weight tensor
    unsigned short* W0b = (unsigned short*)(ws + 1024 + (size_t)T * N * 4);
    unsigned short* Wab = W0b + wsz;
    unsigned short* Wlb = Wab + wsz;
    unsigned short* Wfb = Wlb + wsz;

    hipMemsetAsync(ws, 0, 512, stream);         // padded cursors
    int n4 = (int)(wsz / 4);
    int pb = ((N > n4 ? N : n4) + 255) / 256;
    k_prep<<<pb, 256, 0, stream>>>(species, cursors, perm, N, W0, Wa, Wl, Wf,
                                   W0b, Wab, Wlb, Wfb, n4);

    int nblocks = (N + MT - 1) / MT + T;
    fused_moe<<<nblocks, NTHREADS, 0, stream>>>(density, perm, cursors, W0b, Wab, Wlb, Wfb,
                                                b0, ba, alpha_a, gamma, beta_ln, bl, bfv, alpha_f,
                                                Wo, bo, out, N);
}

// Round 3
// 198.966 us; speedup vs baseline: 1.2738x; 1.0114x over previous
//
#include <hip/hip_runtime.h>
#include <hip/hip_bf16.h>

// Fused per-type MLP chain (Linear -> ResBlock(silu,LN,Linear) -> silu-Linear -> dot)
// R8 (from R7 @ 201us total / fused ~100us, occupancy 35%, MfmaUtil 13.7%):
//  1) XOR-SWIZZLED Xs (T2): old LDSTRIDE=264 gave bank = 4*((ml+h)%8) on GEMM
//     ds_read_b128 => 8-way conflict on EVERY B read (5.25M conflict cycles).
//     New: unpadded [64][256] with halfword col ^ ((row&7)<<3) => 2-way (free).
//  2) PING-PONG buffers Xs[0]/Xs[1]: each phase reads one, writes the other =>
//     1 barrier/phase instead of 2 (13 -> 9 barriers). All per-type vectors
//     staged ONCE up front (no restage races).
//  3) A-PREFETCH: first k-step A-frags of the next GEMM issued before the
//     preceding barrier (weights independent of LDS) -> L2 latency hidden
//     under barrier wait instead of serialized after it.
// MFMA 16x16x32 bf16 layouts (HW-verified per guide m89/m91):
//   A[m][k]: m = lane&15, k = (lane>>4)*8 + j   (W row-major: contiguous 16B)
//   B[k][n]: n = lane&15, k = (lane>>4)*8 + j   (Xs row  : contiguous 16B)
//   C/D:     n(atom) = lane&15, m(neuron) = (lane>>4)*4 + reg

#define D 256
#define T 4
#define MT 64            // atoms per block
#define NTHREADS 512     // 8 waves
#define CSTRIDE 32       // cursor padding: one counter per 128B cache line

// swizzled halfword index for element (row=atom, col=feature halfword)
#define XSW(row, col) (((row) << 8) + ((col) ^ (((row) & 7) << 3)))

typedef __attribute__((ext_vector_type(8))) short bf16x8;
typedef __attribute__((ext_vector_type(4))) float f32x4;

__device__ __forceinline__ float bf2f(unsigned short s) {
    union { unsigned u; float f; } c;
    c.u = ((unsigned)s) << 16;
    return c.f;
}
// packed f32x2 -> bf16x2, RNE (MODE default), 1 instr (guide T12 recipe, m240)
__device__ __forceinline__ unsigned cvtpk(float a, float b) {
    unsigned r;
    asm("v_cvt_pk_bf16_f32 %0, %1, %2" : "=v"(r) : "v"(a), "v"(b));
    return r;
}
__device__ __forceinline__ float lo2f(unsigned u) { return bf2f((unsigned short)(u & 0xffffu)); }
__device__ __forceinline__ float hi2f(unsigned u) { return bf2f((unsigned short)(u >> 16)); }
__device__ __forceinline__ float silu(float v) {
    // fast rcp (~1ulp) is fine: result is rounded to bf16 anyway
    return v * __builtin_amdgcn_rcpf(1.f + __expf(-v));
}

// ---------------- prep kernel (hist+scatter+convert merged) ----------------
// perm layout: capacity regions, type t's atoms at perm[t*N .. t*N+count[t])
extern "C" __global__ void k_prep(const int* __restrict__ species, int* cursors,
                                  int* __restrict__ perm, int N,
                                  const float* __restrict__ s0, const float* __restrict__ s1,
                                  const float* __restrict__ s2, const float* __restrict__ s3,
                                  unsigned short* __restrict__ d0, unsigned short* __restrict__ d1,
                                  unsigned short* __restrict__ d2, unsigned short* __restrict__ d3, int n4) {
    __shared__ int lh[T], lbase[T];
    int tid = threadIdx.x;
    if (tid < T) lh[tid] = 0;
    __syncthreads();
    int i = blockIdx.x * blockDim.x + tid;
    int t = -1, rank = 0;
    if (i < N) {
        t = species[i];
        rank = atomicAdd(&lh[t], 1);          // LDS atomic: block-local rank
    }
    if (i < n4) {   // weight fp32 -> bf16 (vectorized, cvt_pk); independent path
        float4 v;
        v = ((const float4*)s0)[i]; ((uint2*)d0)[i] = make_uint2(cvtpk(v.x, v.y), cvtpk(v.z, v.w));
        v = ((const float4*)s1)[i]; ((uint2*)d1)[i] = make_uint2(cvtpk(v.x, v.y), cvtpk(v.z, v.w));
        v = ((const float4*)s2)[i]; ((uint2*)d2)[i] = make_uint2(cvtpk(v.x, v.y), cvtpk(v.z, v.w));
        v = ((const float4*)s3)[i]; ((uint2*)d3)[i] = make_uint2(cvtpk(v.x, v.y), cvtpk(v.z, v.w));
    }
    __syncthreads();
    if (tid < T) lbase[tid] = atomicAdd(&cursors[tid * CSTRIDE], lh[tid]);  // 4/block, padded lines
    __syncthreads();
    if (t >= 0) perm[t * N + lbase[t] + rank] = i;
}

// ---------------- fused main kernel ----------------

extern "C" __global__ void __launch_bounds__(NTHREADS, 4)
fused_moe(const float* __restrict__ density,
          const int* __restrict__ perm,
          const int* __restrict__ counts,     // == padded cursors after k_prep
          const unsigned short* __restrict__ W0b,
          const unsigned short* __restrict__ Wab,
          const unsigned short* __restrict__ Wlb,
          const unsigned short* __restrict__ Wfb,
          const float* __restrict__ b0g, const float* __restrict__ bag,
          const float* __restrict__ aag, const float* __restrict__ gg,
          const float* __restrict__ btg, const float* __restrict__ blg,
          const float* __restrict__ bfg, const float* __restrict__ afg,
          const float* __restrict__ Wog, const float* __restrict__ bog,
          float* __restrict__ out, int N)
{
    __shared__ unsigned short Xs[2][MT * D];            // 2 x 32768 B, ping-pong, XOR-swizzled
    __shared__ float Pb0[D], Pba[D], Paa[D], Pg[D], Pbt[D], Pbl[D], Pbf[D], Paf[D], Pwo[D]; // 9216 B
    __shared__ float red1[NTHREADS], red2[NTHREADS];    // 4096 B; also carries mu/rs
    // total LDS = 78848 B -> 2 blocks/CU (157.7 <= 160 KB); VGPR<=128 -> 16 waves/CU

    const int tid = threadIdx.x;

    // ---- which (type, tile) am I? ----
    int c[T];
#pragma unroll
    for (int i = 0; i < T; ++i) c[i] = counts[i * CSTRIDE];
    int t = -1, tile = 0, rem = blockIdx.x;
#pragma unroll
    for (int i = 0; i < T; ++i) {
        int ti = (c[i] + MT - 1) >> 6;
        if (t < 0) {
            if (rem < ti) { t = i; tile = rem; }
            else rem -= ti;
        }
    }
    if (t < 0) return;
    const int bstart = t * N + tile * MT;               // capacity-region base
    const int nrows = min(MT, c[t] - tile * MT);

    const int lane = tid & 63;
    const int w    = tid >> 6;            // wave id 0..7 -> neuron 32-slice
    const int ml   = lane & 15;
    const int qk   = (lane >> 4) * 8;     // A/B fragment k offset
    const int qr   = (lane >> 4) * 4;     // C/D fragment neuron offset

    const size_t wmat = (size_t)t * D * D;
    const unsigned short* W0t = W0b + wmat;
    const unsigned short* Wat = Wab + wmat;
    const unsigned short* Wlt = Wlb + wmat;
    const unsigned short* Wft = Wfb + wmat;

    // ---- A-prefetch state (first k-step of next gemm, 8 VGPRs) ----
    bf16x8 pf0, pf1;
    auto prefA = [&](const unsigned short* __restrict__ W) {
        pf0 = *(const bf16x8*)(W + (size_t)(w * 32 + ml) * D + qk);
        pf1 = *(const bf16x8*)(W + (size_t)(w * 32 + 16 + ml) * D + qk);
    };

    prefA(W0t);                                        // hide under gather

    // ---- stage ALL per-type vectors once (512 threads; tid<256 active) ----
    if (tid < D) {
        int j = t * D + tid;
        Pb0[tid] = b0g[j]; Pba[tid] = bag[j]; Paa[tid] = aag[j];
        Pg[tid]  = gg[j];  Pbt[tid] = btg[j]; Pbl[tid] = blg[j];
        Pbf[tid] = bfg[j]; Paf[tid] = afg[j]; Pwo[tid] = Wog[j];
    }

    // ---- gather X0 (fp32 -> bf16) into Xs[0][atom][feature] (swizzled) ----
#pragma unroll
    for (int p = 0; p < 2; ++p) {
        int row = p * 32 + (tid >> 4);
        int cbase = (tid & 15) * 4;
        if (row < nrows) {
            const float* src = density + (size_t)perm[bstart + row] * D;
#pragma unroll
            for (int j = 0; j < 4; ++j) {
                int col = cbase + j * 64;
                float4 v = *(const float4*)(src + col);
                *(uint2*)(&Xs[0][XSW(row, col)]) = make_uint2(cvtpk(v.x, v.y), cvtpk(v.z, v.w));
            }
        } else {
#pragma unroll
            for (int j = 0; j < 4; ++j)
                *(uint2*)(&Xs[0][XSW(row, cbase + j * 64)]) = make_uint2(0u, 0u);
        }
    }
    __syncthreads();                                    // B1

    f32x4 acc[2][4];                      // 32 AGPRs
    const f32x4 zero4 = {0.f, 0.f, 0.f, 0.f};

    // D[m=neuron][n=atom]: A = W rows (global/L2, k0=0 prefetched), B = Xs rows (LDS)
    auto do_gemm = [&](const unsigned short* __restrict__ W, const unsigned short* __restrict__ Xb) {
#pragma unroll
        for (int mi = 0; mi < 2; ++mi)
#pragma unroll
            for (int ni = 0; ni < 4; ++ni) acc[mi][ni] = zero4;
#pragma unroll
        for (int k0 = 0; k0 < D; k0 += 32) {
            bf16x8 a[2], b[4];
            if (k0 == 0) { a[0] = pf0; a[1] = pf1; }
            else {
#pragma unroll
                for (int mi = 0; mi < 2; ++mi)
                    a[mi] = *(const bf16x8*)(W + (size_t)(w * 32 + mi * 16 + ml) * D + k0 + qk);
            }
#pragma unroll
            for (int ni = 0; ni < 4; ++ni)
                b[ni] = *(const bf16x8*)(Xb + XSW(ni * 16 + ml, k0 + qk));
#pragma unroll
            for (int mi = 0; mi < 2; ++mi)
#pragma unroll
                for (int ni = 0; ni < 4; ++ni)
                    acc[mi][ni] = __builtin_amdgcn_mfma_f32_16x16x32_bf16(a[mi], b[ni], acc[mi][ni], 0, 0, 0);
        }
    };

    // lane owns atom a0 = ni*16+ml, neurons r0..r0+3 (contiguous)

    // ======== Phase 1: x1 = X0 @ W0^T + b0   (read Xs0, write Xs1) ========
    do_gemm(W0t, Xs[0]);
    prefA(Wat);
    unsigned res[2][4][2];   // x1 saved PACKED BF16 (16 VGPRs)
#pragma unroll
    for (int mi = 0; mi < 2; ++mi) {
#pragma unroll
        for (int ni = 0; ni < 4; ++ni) {
            int r0 = w * 32 + mi * 16 + qr;
            int a0 = ni * 16 + ml;
            float4 bb = *(const float4*)(Pb0 + r0);
            unsigned p01 = cvtpk(acc[mi][ni][0] + bb.x, acc[mi][ni][1] + bb.y);
            unsigned p23 = cvtpk(acc[mi][ni][2] + bb.z, acc[mi][ni][3] + bb.w);
            res[mi][ni][0] = p01;
            res[mi][ni][1] = p23;
            *(uint2*)(&Xs[1][XSW(a0, r0)]) = make_uint2(p01, p23);
        }
    }
    __syncthreads();                                    // B2

    // ======== Phase 2: h = alpha_a * silu(x1 @ Wa^T + ba)  (read Xs1, write Xs0) ========
    do_gemm(Wat, Xs[1]);
    prefA(Wlt);
#pragma unroll
    for (int mi = 0; mi < 2; ++mi) {
#pragma unroll
        for (int ni = 0; ni < 4; ++ni) {
            int r0 = w * 32 + mi * 16 + qr;
            int a0 = ni * 16 + ml;
            float4 bb = *(const float4*)(Pba + r0);
            float4 aa = *(const float4*)(Paa + r0);
            float v0 = aa.x * silu(acc[mi][ni][0] + bb.x);
            float v1 = aa.y * silu(acc[mi][ni][1] + bb.y);
            float v2 = aa.z * silu(acc[mi][ni][2] + bb.z);
            float v3 = aa.w * silu(acc[mi][ni][3] + bb.w);
            *(uint2*)(&Xs[0][XSW(a0, r0)]) = make_uint2(cvtpk(v0, v1), cvtpk(v2, v3));
        }
    }
    __syncthreads();                                    // B3

    // ======== LayerNorm per atom (read Xs0, write Xs1) ========
    {
        int row = tid & 63, q = tid >> 6;   // thread covers 32 columns
        bf16x8 hv[4];
        float sum = 0.f, ssq = 0.f;
#pragma unroll
        for (int j = 0; j < 4; ++j) {
            hv[j] = *(const bf16x8*)(&Xs[0][XSW(row, q * 32 + j * 8)]);
#pragma unroll
            for (int e = 0; e < 8; ++e) {
                float f = bf2f((unsigned short)hv[j][e]);
                sum += f;
                ssq = fmaf(f, f, ssq);
            }
        }
        red1[tid] = sum; red2[tid] = ssq;
        __syncthreads();                                // B4
        if (tid < MT) {
            float s = 0.f, sq = 0.f;
#pragma unroll
            for (int k = 0; k < 8; ++k) { s += red1[tid + 64 * k]; sq += red2[tid + 64 * k]; }
            float mu = s * (1.f / D);
            float var = sq * (1.f / D) - mu * mu;
            red1[tid] = mu;
            red2[tid] = rsqrtf(var + 1e-5f);
        }
        __syncthreads();                                // B5
        float mu = red1[row], rs = red2[row];
#pragma unroll
        for (int j = 0; j < 4; ++j) {
            float n[8];
#pragma unroll
            for (int e = 0; e < 8; ++e) {
                int col = q * 32 + j * 8 + e;
                float f = bf2f((unsigned short)hv[j][e]);
                n[e] = fmaf((f - mu) * rs, Pg[col], Pbt[col]);
            }
            uint4 o = make_uint4(cvtpk(n[0], n[1]), cvtpk(n[2], n[3]),
                                 cvtpk(n[4], n[5]), cvtpk(n[6], n[7]));
            *(uint4*)(&Xs[1][XSW(row, q * 32 + j * 8)]) = o;
        }
    }
    __syncthreads();                                    // B6

    // ======== Phase 3: x3 = x1 + h @ Wl^T + bl  (read Xs1, write Xs0) ========
    do_gemm(Wlt, Xs[1]);
    prefA(Wft);
#pragma unroll
    for (int mi = 0; mi < 2; ++mi) {
#pragma unroll
        for (int ni = 0; ni < 4; ++ni) {
            int r0 = w * 32 + mi * 16 + qr;
            int a0 = ni * 16 + ml;
            float4 bb = *(const float4*)(Pbl + r0);
            float v0 = acc[mi][ni][0] + bb.x + lo2f(res[mi][ni][0]);
            float v1 = acc[mi][ni][1] + bb.y + hi2f(res[mi][ni][0]);
            float v2 = acc[mi][ni][2] + bb.z + lo2f(res[mi][ni][1]);
            float v3 = acc[mi][ni][3] + bb.w + hi2f(res[mi][ni][1]);
            *(uint2*)(&Xs[0][XSW(a0, r0)]) = make_uint2(cvtpk(v0, v1), cvtpk(v2, v3));
        }
    }
    __syncthreads();                                    // B7

    // ======== Phase 4: x4 = alpha_f * silu(x3 @ Wf^T + bf)  (read Xs0, write Xs1) ========
    do_gemm(Wft, Xs[0]);
#pragma unroll
    for (int mi = 0; mi < 2; ++mi) {
#pragma unroll
        for (int ni = 0; ni < 4; ++ni) {
            int r0 = w * 32 + mi * 16 + qr;
            int a0 = ni * 16 + ml;
            float4 bb = *(const float4*)(Pbf + r0);
            float4 aa = *(const float4*)(Paf + r0);
            float v0 = aa.x * silu(acc[mi][ni][0] + bb.x);
            float v1 = aa.y * silu(acc[mi][ni][1] + bb.y);
            float v2 = aa.z * silu(acc[mi][ni][2] + bb.z);
            float v3 = aa.w * silu(acc[mi][ni][3] + bb.w);
            *(uint2*)(&Xs[1][XSW(a0, r0)]) = make_uint2(cvtpk(v0, v1), cvtpk(v2, v3));
        }
    }
    __syncthreads();                                    // B8

    // ======== Output: y = x4 . Wo[t] + bo[t]  (read Xs1) ========
    {
        int row = tid & 63, q = tid >> 6;
        float part = 0.f;
#pragma unroll
        for (int j = 0; j < 4; ++j) {
            bf16x8 hv = *(const bf16x8*)(&Xs[1][XSW(row, q * 32 + j * 8)]);
#pragma unroll
            for (int e = 0; e < 8; ++e)
                part = fmaf(bf2f((unsigned short)hv[e]), Pwo[q * 32 + j * 8 + e], part);
        }
        red1[tid] = part;
        __syncthreads();                                // B9
        if (tid < nrows) {
            float val = bog[t];
#pragma unroll
            for (int k = 0; k < 8; ++k) val += red1[tid + 64 * k];
            out[perm[bstart + tid]] = val;
        }
    }
}

// ---------------- launcher ----------------

extern "C" void kernel_launch(void* const* d_in, const int* in_sizes, int n_in,
                              void* d_out, int out_size, void* d_ws, size_t ws_size,
                              hipStream_t stream) {
    const float* density = (const float*)d_in[0];
    const int*   species = (const int*)d_in[1];
    const float* W0      = (const float*)d_in[2];
    const float* b0      = (const float*)d_in[3];
    const float* Wa      = (const float*)d_in[4];
    const float* ba      = (const float*)d_in[5];
    const float* alpha_a = (const float*)d_in[6];
    const float* gamma   = (const float*)d_in[7];
    const float* beta_ln = (const float*)d_in[8];
    const float* Wl      = (const float*)d_in[9];
    const float* bl      = (const float*)d_in[10];
    const float* Wf      = (const float*)d_in[11];
    const float* bfv     = (const float*)d_in[12];
    const float* alpha_f = (const float*)d_in[13];
    const float* Wo      = (const float*)d_in[14];
    const float* bo      = (const float*)d_in[15];
    float* out = (float*)d_out;
    const int N = in_sizes[1];

    // ws layout: [cursors 4 x 128B = 512B, pad to 1KB] [perm T*N ints = 1MB]
    //            [bf16 weights 4 x 512KB]
    char* ws = (char*)d_ws;
    int* cursors = (int*)ws;
    int* perm    = (int*)(ws + 1024);
    const size_t wsz = (size_t)T * D * D;       // elems per weight tensor
    unsigned short* W0b = (unsigned short*)(ws + 1024 + (size_t)T * N * 4);
    unsigned short* Wab = W0b + wsz;
    unsigned short* Wlb = Wab + wsz;
    unsigned short* Wfb = Wlb + wsz;

    hipMemsetAsync(ws, 0, 512, stream);         // padded cursors
    int n4 = (int)(wsz / 4);
    int pb = ((N > n4 ? N : n4) + 255) / 256;
    k_prep<<<pb, 256, 0, stream>>>(species, cursors, perm, N, W0, Wa, Wl, Wf,
                                   W0b, Wab, Wlb, Wfb, n4);

    int nblocks = (N + MT - 1) / MT + T;
    fused_moe<<<nblocks, NTHREADS, 0, stream>>>(density, perm, cursors, W0b, Wab, Wlb, Wfb,
                                                b0, ba, alpha_a, gamma, beta_ln, bl, bfv, alpha_f,
                                                Wo, bo, out, N);
}